// Round 11
// baseline (283.531 us; speedup 1.0000x reference)
//
#include <hip/hip_runtime.h>
#include <hip/hip_fp16.h>
#include <math.h>

// Problem constants
#define BDIM 2
#define TDIM 2048
#define CDIM 1024
#define HDIM 16
#define DDIM 64

typedef _Float16 f16x8 __attribute__((ext_vector_type(8)));
typedef _Float16 f16x4 __attribute__((ext_vector_type(4)));
typedef float f32x4 __attribute__((ext_vector_type(4)));

#define GLL16(gsrc, ldst)                                                      \
  __builtin_amdgcn_global_load_lds(                                            \
      (const __attribute__((address_space(1))) unsigned int*)(gsrc),           \
      (__attribute__((address_space(3))) unsigned int*)(ldst), 16, 0, 0)

// XOR swizzle for 128B-stride LDS tiles: spreads 16B slots across banks.
#define SWZ(row) ((((row)&7) ^ (((row) >> 3) & 7)) << 4)

// scale * log2(e): softmax computed in exp2 domain (exactly equivalent)
#define SCALE_LOG2E 0.1803368801111204f

// ---------------------------------------------------------------------------
// fp32 -> fp16 elementwise convert (8 elems/thread)
// ---------------------------------------------------------------------------
__global__ __launch_bounds__(256) void cvt_f16(const float* __restrict__ in,
                                               __half* __restrict__ out,
                                               int n8) {
  int i = blockIdx.x * blockDim.x + threadIdx.x;
  if (i >= n8) return;
  const float4* p = (const float4*)in + (size_t)i * 2;
  float4 a = p[0], b = p[1];
  __half2* o = (__half2*)out + (size_t)i * 4;
  o[0] = __floats2half2_rn(a.x, a.y);
  o[1] = __floats2half2_rn(a.z, a.w);
  o[2] = __floats2half2_rn(b.x, b.y);
  o[3] = __floats2half2_rn(b.z, b.w);
}

// ---------------------------------------------------------------------------
// W [K][N] f32  ->  Wt [N][K] f16   (z selects which of 4 matrices)
// ---------------------------------------------------------------------------
__global__ __launch_bounds__(256) void transpose_cvt(
    const float* __restrict__ w0, const float* __restrict__ w1,
    const float* __restrict__ w2, const float* __restrict__ w3,
    __half* __restrict__ o0, __half* __restrict__ o1, __half* __restrict__ o2,
    __half* __restrict__ o3) {
  const float* src;
  __half* dst;
  switch (blockIdx.z) {
    case 0: src = w0; dst = o0; break;
    case 1: src = w1; dst = o1; break;
    case 2: src = w2; dst = o2; break;
    default: src = w3; dst = o3; break;
  }
  __shared__ float t[32][33];
  const int tx = threadIdx.x & 31, ty = threadIdx.x >> 5;  // 32 x 8
  const int k0 = blockIdx.y * 32, n0 = blockIdx.x * 32;
#pragma unroll
  for (int j = 0; j < 4; ++j)
    t[ty + j * 8][tx] = src[(size_t)(k0 + ty + j * 8) * CDIM + n0 + tx];
  __syncthreads();
#pragma unroll
  for (int j = 0; j < 4; ++j)
    dst[(size_t)(n0 + ty + j * 8) * CDIM + k0 + tx] =
        __float2half(t[tx][ty + j * 8]);
}

// ---------------------------------------------------------------------------
// MFMA GEMM, 2-phase prefetch: out = A16[M][K] @ Bt16[N][K]^T + bias.
// BM=128, BN templated (128 or 64), BK=32, 4 waves, mfma_f32_16x16x32_f16.
// NMAT=3 fuses QKV (BN=128): Bt rows = [WqT;WkT;WvT]; Q,K written row-major
// [tok][C]; V written TRANSPOSED [C][NTOK] (f16x4 quads: the 4 j-values of a
// fragment are consecutive tokens) so attention can GLL-stage V^T directly.
// ---------------------------------------------------------------------------
template <int NMAT, int OUT16, int BN>
__global__ __launch_bounds__(256) void gemm_f16_bt(
    const __half* __restrict__ A, const __half* __restrict__ Bt,
    const float* __restrict__ bias0, const float* __restrict__ bias1,
    const float* __restrict__ bias2, float* __restrict__ outf,
    __half* __restrict__ outh, int M, int K) {
  constexpr int NB = BN / 32;  // B fragments per wave
  constexpr int BG = BN / 64;  // B GLLs per wave
  __shared__ _Float16 As[2][128][32];
  __shared__ _Float16 Bs[2][BN][32];
  const int tid = threadIdx.x;
  const int wid = tid >> 6, lane = tid & 63;
  const int m0 = blockIdx.y * 128, n0 = blockIdx.x * BN;
  const int wr = (wid >> 1) * 64, wc = (wid & 1) * (BN / 2);
  const int srow = lane >> 2;
  const int scol = (lane & 3) * 8;

  const __half* asrc = A + (size_t)(m0 + wid * 32 + srow) * K + scol;
  const __half* bsrc = Bt + (size_t)(n0 + srow) * K + scol;

  f32x4 acc[4][NB] = {};
  const int NT = K / 32;

  GLL16(asrc, &As[0][wid * 32][0]);
  GLL16(asrc + 16 * K, &As[0][wid * 32 + 16][0]);
#pragma unroll
  for (int i = 0; i < BG; ++i) {
    const int row0 = wid * (16 * BG) + i * 16;
    GLL16(bsrc + (size_t)row0 * K, &Bs[0][row0][0]);
  }
  __syncthreads();  // barrier lowering drains vmcnt(0)

  for (int t = 0; t < NT; ++t) {
    const int cur = t & 1;
    if (t + 1 < NT) {
      const int k0 = (t + 1) * 32;
      GLL16(asrc + k0, &As[cur ^ 1][wid * 32][0]);
      GLL16(asrc + k0 + 16 * K, &As[cur ^ 1][wid * 32 + 16][0]);
#pragma unroll
      for (int i = 0; i < BG; ++i) {
        const int row0 = wid * (16 * BG) + i * 16;
        GLL16(bsrc + (size_t)row0 * K + k0, &Bs[cur ^ 1][row0][0]);
      }
    }
    f16x8 a[4], b[NB];
#pragma unroll
    for (int m = 0; m < 4; ++m)
      a[m] =
          *(const f16x8*)&As[cur][wr + m * 16 + (lane & 15)][(lane >> 4) * 8];
#pragma unroll
    for (int n = 0; n < NB; ++n)
      b[n] =
          *(const f16x8*)&Bs[cur][wc + n * 16 + (lane & 15)][(lane >> 4) * 8];
#pragma unroll
    for (int m = 0; m < 4; ++m)
#pragma unroll
      for (int n = 0; n < NB; ++n)
        acc[m][n] = __builtin_amdgcn_mfma_f32_16x16x32_f16(a[m], b[n],
                                                           acc[m][n], 0, 0, 0);
    __syncthreads();
  }

  const float* bias = bias0;
  size_t obase = 0;
  int ncol0 = n0;
  int mat = 0;
  if (NMAT == 3) {
    mat = n0 >> 10;
    bias = (mat == 0) ? bias0 : (mat == 1) ? bias1 : bias2;
    obase = (size_t)mat * ((size_t)M * CDIM);
    ncol0 = n0 & 1023;
  }
  if (NMAT == 3 && mat == 2) {
    // V: write transposed [C][NTOK] as f16x4 token-quads
#pragma unroll
    for (int m = 0; m < 4; ++m)
#pragma unroll
      for (int n = 0; n < NB; ++n) {
        const int col = ncol0 + wc + n * 16 + (lane & 15);
        const float bb = bias[col];
        const int row0 = m0 + wr + m * 16 + (lane >> 4) * 4;
        f16x4 qv;
#pragma unroll
        for (int j = 0; j < 4; ++j) qv[j] = (_Float16)(acc[m][n][j] + bb);
        *(f16x4*)(outh + obase + (size_t)col * M + row0) = qv;
      }
  } else {
#pragma unroll
    for (int m = 0; m < 4; ++m)
#pragma unroll
      for (int n = 0; n < NB; ++n) {
        const int col = ncol0 + wc + n * 16 + (lane & 15);
        const float bb = bias[col];
#pragma unroll
        for (int j = 0; j < 4; ++j) {
          const int row = m0 + wr + m * 16 + (lane >> 4) * 4 + j;
          if (OUT16)
            outh[obase + (size_t)row * CDIM + col] =
                __float2half(acc[m][n][j] + bb);
          else
            outf[(size_t)row * CDIM + col] = acc[m][n][j] + bb;
        }
      }
  }
}

// ---------------------------------------------------------------------------
// MFMA flash attention, swapped operands: S^T = mfma(K,Q), ctx^T = mfma(Vt,Pt).
// K staged row-major [k][d], V^T staged [d][k] DIRECTLY from the transposed
// global v16T[C][NTOK] — both via global_load_lds with inverse-swizzled
// source (identical lane mapping), double-buffered. No scalar transpose, no
// mid-tile vmcnt. P routed through per-wave swizzled LDS (b64 quads).
// ---------------------------------------------------------------------------
__global__ __launch_bounds__(256) void attention_mfma(
    const __half* __restrict__ q, const __half* __restrict__ k,
    const __half* __restrict__ vT, __half* __restrict__ ctx) {
  __shared__ _Float16 Kl[2][64][64];  // [k-row][d], swizzled 16B chunks
  __shared__ _Float16 Vt[2][64][64];  // [d][k-row], swizzled 16B chunks
  __shared__ _Float16 Pl[4][16][64];  // per-wave [q][k], swizzled rows

  const int tid = threadIdx.x;
  const int wid = tid >> 6, lane = tid & 63;
  const int qt = (blockIdx.x + blockIdx.y) & 31;  // balanced per-CU causal mix
  const int bh = blockIdx.y;
  const int b = bh >> 4, h = bh & 15;
  const int qbase = qt * 64;
  const int g = lane >> 4, r = lane & 15;

  const __half* qhead = q + ((size_t)b * TDIM) * CDIM + h * DDIM;
  const __half* khead = k + ((size_t)b * TDIM) * CDIM + h * DDIM;
  // v16T layout [C][NTOK]: head rows h*64..+63, token base b*TDIM
  const size_t NTOK = (size_t)BDIM * TDIM;
  const __half* vhead = vT + (size_t)(h * DDIM) * NTOK + (size_t)b * TDIM;

  // Q fragment (B-operand of S^T): row qbase+wid*16+r, elems g*8 + kk*32
  f16x8 qf[2];
  {
    const __half* qrow = qhead + (size_t)(qbase + wid * 16 + r) * CDIM;
    qf[0] = *(const f16x8*)(qrow + g * 8);
    qf[1] = *(const f16x8*)(qrow + g * 8 + 32);
  }

  // GLL lane mapping (shared by K and V^T): call c covers rows c*8..c*8+7;
  // lane covers row c*8 + (lane>>3), physical 16B chunk lane&7; source chunk
  // is inverse-swizzled so that swizzled reads see logical data.
  const int r8 = lane >> 3;
  const int c0 = wid * 2, c1 = wid * 2 + 1;
  const int col0 = (((lane & 7) ^ r8 ^ c0) & 7) * 8;
  const int col1 = (((lane & 7) ^ r8 ^ c1) & 7) * 8;

  f32x4 accT[4] = {};  // accT[n][j]: d = n*16+g*4+j, q-row = r
  float m = -3.0e38f, l = 0.0f;

  const int nt = qt + 1;

  // ---- prologue: stage tile 0 (4 GLL/wave: 2 K + 2 V^T) ----
  GLL16(khead + (size_t)(c0 * 8 + r8) * CDIM + col0, &Kl[0][c0 * 8][0]);
  GLL16(khead + (size_t)(c1 * 8 + r8) * CDIM + col1, &Kl[0][c1 * 8][0]);
  GLL16(vhead + (size_t)(c0 * 8 + r8) * NTOK + col0, &Vt[0][c0 * 8][0]);
  GLL16(vhead + (size_t)(c1 * 8 + r8) * NTOK + col1, &Vt[0][c1 * 8][0]);
  __syncthreads();

  for (int t = 0; t < nt; ++t) {
    const int cur = t & 1, nxt = cur ^ 1;
    // ---- issue next-tile staging (stays in flight over compute) ----
    if (t + 1 < nt) {
      const size_t koff = (size_t)((t + 1) * 64);
      GLL16(khead + (koff + c0 * 8 + r8) * CDIM + col0, &Kl[nxt][c0 * 8][0]);
      GLL16(khead + (koff + c1 * 8 + r8) * CDIM + col1, &Kl[nxt][c1 * 8][0]);
      GLL16(vhead + (size_t)(c0 * 8 + r8) * NTOK + koff + col0,
            &Vt[nxt][c0 * 8][0]);
      GLL16(vhead + (size_t)(c1 * 8 + r8) * NTOK + koff + col1,
            &Vt[nxt][c1 * 8][0]);
    }

    // ---- S^T[64k x 16q] = K @ Q^T ----
    f32x4 sT[4] = {};
    const char* klb = (const char*)&Kl[cur][0][0];
#pragma unroll
    for (int kk = 0; kk < 2; ++kk) {
#pragma unroll
      for (int kb = 0; kb < 4; ++kb) {
        const int krow = kb * 16 + r;
        f16x8 kf = *(const f16x8*)(klb + krow * 128 +
                                   ((g * 16 + kk * 64) ^ SWZ(krow)));
        sT[kb] =
            __builtin_amdgcn_mfma_f32_16x16x32_f16(kf, qf[kk], sT[kb], 0, 0, 0);
      }
    }

    // ---- scale (exp2 domain) + causal mask (diagonal tile only) ----
    const int qg = qbase + wid * 16 + r;
    if (t == qt) {
#pragma unroll
      for (int kb = 0; kb < 4; ++kb) {
        const int kg = t * 64 + kb * 16 + g * 4;
#pragma unroll
        for (int j = 0; j < 4; ++j)
          sT[kb][j] = (kg + j <= qg) ? sT[kb][j] * SCALE_LOG2E : -3.0e38f;
      }
    } else {
#pragma unroll
      for (int kb = 0; kb < 4; ++kb)
#pragma unroll
        for (int j = 0; j < 4; ++j) sT[kb][j] *= SCALE_LOG2E;
    }

    // ---- online softmax: per-lane row state, 2+2 shfl over g ----
    float mx = sT[0][0];
#pragma unroll
    for (int kb = 0; kb < 4; ++kb)
#pragma unroll
      for (int j = 0; j < 4; ++j) mx = fmaxf(mx, sT[kb][j]);
    mx = fmaxf(mx, __shfl_xor(mx, 16));
    mx = fmaxf(mx, __shfl_xor(mx, 32));
    const float mnew = fmaxf(m, mx);
    const float corr = exp2f(m - mnew);
    float psum = 0.f;
    float pv[4][4];
#pragma unroll
    for (int kb = 0; kb < 4; ++kb)
#pragma unroll
      for (int j = 0; j < 4; ++j) {
        pv[kb][j] = exp2f(sT[kb][j] - mnew);
        psum += pv[kb][j];
      }
    psum += __shfl_xor(psum, 16);
    psum += __shfl_xor(psum, 32);
    l = l * corr + psum;
    m = mnew;
#pragma unroll
    for (int n = 0; n < 4; ++n) accT[n] *= corr;

    // ---- P^T route: 4x ds_write_b64 quads into per-wave Pl[q=r][k] ----
    char* pb = (char*)&Pl[wid][0][0];
#pragma unroll
    for (int kb = 0; kb < 4; ++kb) {
      f16x4 pq;
#pragma unroll
      for (int j = 0; j < 4; ++j) pq[j] = (_Float16)pv[kb][j];
      *(f16x4*)(pb + r * 128 + ((kb * 32 + g * 8) ^ SWZ(r))) = pq;
    }

    // ---- ctx^T += V^T @ P^T ----
    const char* vtb = (const char*)&Vt[cur][0][0];
#pragma unroll
    for (int kk = 0; kk < 2; ++kk) {
      f16x8 pa = *(const f16x8*)(pb + r * 128 + ((g * 16 + kk * 64) ^ SWZ(r)));
#pragma unroll
      for (int n = 0; n < 4; ++n) {
        const int vd = n * 16 + r;
        f16x8 vf =
            *(const f16x8*)(vtb + vd * 128 + ((g * 16 + kk * 64) ^ SWZ(vd)));
        accT[n] =
            __builtin_amdgcn_mfma_f32_16x16x32_f16(vf, pa, accT[n], 0, 0, 0);
      }
    }
    __syncthreads();  // drains own GLLs (had full compute to land) + buf reuse
  }

  // ---- epilogue: normalize, write fp16 ctx (8B quads) ----
  const float inv = 1.0f / l;
  const int qg = qbase + wid * 16 + r;
  __half* orow = ctx + ((size_t)(b * TDIM + qg)) * CDIM + h * DDIM;
#pragma unroll
  for (int n = 0; n < 4; ++n) {
    f16x4 ov;
#pragma unroll
    for (int j = 0; j < 4; ++j) ov[j] = (_Float16)(accT[n][j] * inv);
    *(f16x4*)(orow + n * 16 + g * 4) = ov;
  }
}

// ---------------------------------------------------------------------------
extern "C" void kernel_launch(void* const* d_in, const int* in_sizes, int n_in,
                              void* d_out, int out_size, void* d_ws,
                              size_t ws_size, hipStream_t stream) {
  // 0 hs, 1 mask(unused: implicit causal), 2 Wq, 3 bq, 4 Wk, 5 bk, 6 Wv, 7 bv,
  // 8 Wo, 9 bo, 10..13 routing MLP (dead code)
  const float* hs = (const float*)d_in[0];
  const float* Wq = (const float*)d_in[2];
  const float* bq = (const float*)d_in[3];
  const float* Wk = (const float*)d_in[4];
  const float* bk = (const float*)d_in[5];
  const float* Wv = (const float*)d_in[6];
  const float* bv = (const float*)d_in[7];
  const float* Wo = (const float*)d_in[8];
  const float* bo = (const float*)d_in[9];
  float* out = (float*)d_out;

  const size_t NTOK = (size_t)BDIM * TDIM;  // 4096
  const size_t NELEM = NTOK * CDIM;         // 4M

  __half* q16 = (__half*)d_ws;        // [NTOK][C]
  __half* k16 = q16 + NELEM;          // [NTOK][C]
  __half* v16 = k16 + NELEM;          // TRANSPOSED [C][NTOK]
  __half* hs16 = v16 + NELEM;
  __half* ctx16 = hs16 + NELEM;
  __half* wqt = ctx16 + NELEM;
  __half* wkt = wqt + (size_t)CDIM * CDIM;
  __half* wvt = wkt + (size_t)CDIM * CDIM;
  __half* wot = wvt + (size_t)CDIM * CDIM;

  cvt_f16<<<dim3((NELEM / 8 + 255) / 256), dim3(256), 0, stream>>>(
      hs, hs16, (int)(NELEM / 8));
  transpose_cvt<<<dim3(32, 32, 4), dim3(256), 0, stream>>>(
      Wq, Wk, Wv, Wo, wqt, wkt, wvt, wot);

  dim3 gblk(256);
  // fused QKV: N=3072, Q/K row-major, V transposed (see epilogue)
  gemm_f16_bt<3, 1, 128><<<dim3(24, 32), gblk, 0, stream>>>(
      hs16, wqt, bq, bk, bv, nullptr, q16, (int)NTOK, CDIM);

  attention_mfma<<<dim3(TDIM / 64, BDIM * HDIM), dim3(256), 0, stream>>>(
      q16, k16, v16, ctx16);

  // Wo: BN=64 -> 512 blocks (2/CU)
  gemm_f16_bt<1, 0, 64><<<dim3(16, 32), gblk, 0, stream>>>(
      ctx16, wot, bo, bo, bo, out, nullptr, (int)NTOK, CDIM);
}